// Round 8
// baseline (85.195 us; speedup 1.0000x reference)
//
#include <hip/hip_runtime.h>
#include <hip/hip_bf16.h>

// RSynaptic single-step with zero initial state collapses to elementwise:
//   syn = x + conv_b[t]            (alpha*syn0 = 0; conv(spk0=0) = 0 + bias)
//   reset = (0 - threshold > 0)    (uniform scalar, detached)
//   mem = syn - reset*threshold    (beta*mem0 = 0)
//   spk = (mem - threshold > 0) ? 1 : 0
// Shapes: x [B=4, T=112, N=2048, F=32]; conv_b indexed by T.
// Output: concat(spk, mem, syn) flat, fp32. Pure streaming: 1 read + 3 writes.
//
// R7 result: normal loads (x L3-resident, 117 MB < 256 MB IC) + nt stores
// = 76.5 us. R8: n4 = 7 * 2^20 exactly -> hardcode stride, fully unroll the
// 7 iterations: 7 loads issued up front (MLP), then 21 nt stores grouped by
// stream. Target the ~50 us write-stream floor.

#define NF_SHIFT 16              // N*F = 2048*32 = 65536 = 2^16
#define T_DIM 112
#define GRID 4096
#define BLOCK 256
#define STRIDE4 (GRID * BLOCK)   // 2^20 float4s per sweep
#define ITERS 7

typedef float f4 __attribute__((ext_vector_type(4)));

__global__ __launch_bounds__(BLOCK) void SynapticSpike_unroll7(
    const f4* __restrict__ x,
    const float* __restrict__ conv_b,
    const float* __restrict__ thr_p,
    f4* __restrict__ out,
    int s4) {

    const float thr = thr_p[0];
    const float rt = ((0.0f - thr) > 0.0f ? 1.0f : 0.0f) * thr;   // detached reset

    const int base = blockIdx.x * BLOCK + threadIdx.x;

    // Issue all 7 loads first: 112 B/lane in flight.
    f4 xv[ITERS];
#pragma unroll
    for (int j = 0; j < ITERS; ++j)
        xv[j] = x[base + j * STRIDE4];

    f4 syn[ITERS], mem[ITERS], spk[ITERS];
#pragma unroll
    for (int j = 0; j < ITERS; ++j) {
        int i = base + j * STRIDE4;
        int t = (i >> (NF_SHIFT - 2)) % T_DIM;   // wave-uniform slab index
        float bias = conv_b[t];
        syn[j] = xv[j] + bias;
        mem[j] = syn[j] - rt;
        spk[j].x = (mem[j].x - thr) > 0.0f ? 1.0f : 0.0f;
        spk[j].y = (mem[j].y - thr) > 0.0f ? 1.0f : 0.0f;
        spk[j].z = (mem[j].z - thr) > 0.0f ? 1.0f : 0.0f;
        spk[j].w = (mem[j].w - thr) > 0.0f ? 1.0f : 0.0f;
    }

    // Stores grouped by output stream; all nontemporal (don't evict x from L3).
#pragma unroll
    for (int j = 0; j < ITERS; ++j)
        __builtin_nontemporal_store(spk[j], &out[base + j * STRIDE4]);
#pragma unroll
    for (int j = 0; j < ITERS; ++j)
        __builtin_nontemporal_store(mem[j], &out[s4 + base + j * STRIDE4]);
#pragma unroll
    for (int j = 0; j < ITERS; ++j)
        __builtin_nontemporal_store(syn[j], &out[2 * s4 + base + j * STRIDE4]);
}

// Generic fallback (any size) — same math, grid-stride.
__global__ __launch_bounds__(BLOCK) void SynapticSpike_generic(
    const f4* __restrict__ x,
    const float* __restrict__ conv_b,
    const float* __restrict__ thr_p,
    f4* __restrict__ out,
    int n4, int s4) {

    const float thr = thr_p[0];
    const float rt = ((0.0f - thr) > 0.0f ? 1.0f : 0.0f) * thr;

    const int stride = gridDim.x * blockDim.x;
    for (int i = blockIdx.x * blockDim.x + threadIdx.x; i < n4; i += stride) {
        int t = (i >> (NF_SHIFT - 2)) % T_DIM;
        float bias = conv_b[t];
        f4 xv = x[i];
        f4 syn = xv + bias;
        f4 mem = syn - rt;
        f4 spk;
        spk.x = (mem.x - thr) > 0.0f ? 1.0f : 0.0f;
        spk.y = (mem.y - thr) > 0.0f ? 1.0f : 0.0f;
        spk.z = (mem.z - thr) > 0.0f ? 1.0f : 0.0f;
        spk.w = (mem.w - thr) > 0.0f ? 1.0f : 0.0f;
        __builtin_nontemporal_store(spk, &out[i]);
        __builtin_nontemporal_store(mem, &out[s4 + i]);
        __builtin_nontemporal_store(syn, &out[2 * s4 + i]);
    }
}

extern "C" void kernel_launch(void* const* d_in, const int* in_sizes, int n_in,
                              void* d_out, int out_size, void* d_ws, size_t ws_size,
                              hipStream_t stream) {
    // inputs: x, alpha, beta, conv_w, conv_b, threshold
    const f4* x = (const f4*)d_in[0];
    const float* conv_b = (const float*)d_in[4];
    const float* thr = (const float*)d_in[5];
    f4* out = (f4*)d_out;

    const int S = in_sizes[0];        // B*T*N*F = 29,360,128
    const int n4 = S / 4;             // 7,340,032 float4s per output tensor
    const int s4 = n4;

    if (n4 == ITERS * STRIDE4) {
        SynapticSpike_unroll7<<<GRID, BLOCK, 0, stream>>>(x, conv_b, thr, out, s4);
    } else {
        const int grid = (n4 + BLOCK - 1) / BLOCK > 4096 ? 4096 : (n4 + BLOCK - 1) / BLOCK;
        SynapticSpike_generic<<<grid, BLOCK, 0, stream>>>(x, conv_b, thr, out, n4, s4);
    }
}

// Round 9
// 72.032 us; speedup vs baseline: 1.1827x; 1.1827x over previous
//
#include <hip/hip_runtime.h>
#include <hip/hip_bf16.h>

// RSynaptic single-step with zero initial state collapses to elementwise:
//   syn = x + conv_b[t]            (alpha*syn0 = 0; conv(spk0=0) = 0 + bias)
//   reset = (0 - threshold > 0)    (uniform scalar, detached)
//   mem = syn - reset*threshold    (beta*mem0 = 0)
//   spk = (mem - threshold > 0) ? 1 : 0
// Shapes: x [B=4, T=112, N=2048, F=32]; conv_b indexed by T.
// Output: concat(spk, mem, syn) flat, fp32. 1 read (L3-resident) + 3 writes.
//
// Ladder: R1 (1 f4/thread, normal ld+st)            = 91.1 us
//         R2 (grid-stride 7, nt ld + nt st)         = 90.6 us
//         R7 (grid-stride 7, normal ld + nt st)     = 76.5 us  <- cache policy wins
//         R8 (unroll7, reg-blocked, normal+nt)      = 85.2 us  <- VGPR/occupancy hurt
// R9: R7's cache policy at MAX TLP: one float4 per thread, 28672 blocks.
// Tests whether the write stream needs more waves in flight to reach its
// ~7 TB/s pure-write rate. If neutral -> fabric roofline (470 MB @ 6.2 TB/s).

#define NF_SHIFT 16              // N*F = 2048*32 = 65536 = 2^16
#define T_DIM 112
#define BLOCK 256

typedef float f4 __attribute__((ext_vector_type(4)));

__global__ __launch_bounds__(BLOCK) void SynapticSpike_flat(
    const f4* __restrict__ x,
    const float* __restrict__ conv_b,
    const float* __restrict__ thr_p,
    f4* __restrict__ out,
    int n4, int s4) {

    int i = blockIdx.x * BLOCK + threadIdx.x;
    if (i >= n4) return;

    const float thr = thr_p[0];
    const float rt = ((0.0f - thr) > 0.0f ? 1.0f : 0.0f) * thr;   // detached reset

    int t = (i >> (NF_SHIFT - 2)) % T_DIM;   // wave-uniform slab index
    float bias = conv_b[t];

    f4 xv = x[i];                 // normal load: x stays L3-resident across replays

    f4 syn = xv + bias;
    f4 mem = syn - rt;
    f4 spk;
    spk.x = (mem.x - thr) > 0.0f ? 1.0f : 0.0f;
    spk.y = (mem.y - thr) > 0.0f ? 1.0f : 0.0f;
    spk.z = (mem.z - thr) > 0.0f ? 1.0f : 0.0f;
    spk.w = (mem.w - thr) > 0.0f ? 1.0f : 0.0f;

    __builtin_nontemporal_store(spk, &out[i]);            // spikes
    __builtin_nontemporal_store(mem, &out[s4 + i]);       // membrane
    __builtin_nontemporal_store(syn, &out[2 * s4 + i]);   // synaptic
}

extern "C" void kernel_launch(void* const* d_in, const int* in_sizes, int n_in,
                              void* d_out, int out_size, void* d_ws, size_t ws_size,
                              hipStream_t stream) {
    // inputs: x, alpha, beta, conv_w, conv_b, threshold
    const f4* x = (const f4*)d_in[0];
    const float* conv_b = (const float*)d_in[4];
    const float* thr = (const float*)d_in[5];
    f4* out = (f4*)d_out;

    const int S = in_sizes[0];        // B*T*N*F = 29,360,128
    const int n4 = S / 4;             // 7,340,032 float4s per output tensor
    const int s4 = n4;

    const int grid = (n4 + BLOCK - 1) / BLOCK;   // 28672 blocks
    SynapticSpike_flat<<<grid, BLOCK, 0, stream>>>(x, conv_b, thr, out, n4, s4);
}